// Round 27
// baseline (97.215 us; speedup 1.0000x reference)
//
#include <hip/hip_runtime.h>
#include <math.h>

#define B_ 4
#define L_ 4096
#define D_ 256
#define N_ 16
#define DTR 16
#define NC 128
#define LC 32
#define NCH 256
#define LCH 16
#define M_ (B_*L_)

typedef __attribute__((ext_vector_type(8))) short short8;
typedef __attribute__((ext_vector_type(4))) float floatx4;

__device__ __forceinline__ float silu_f(float v) { return v / (1.f + __expf(-v)); }

__device__ __forceinline__ unsigned short f2bf(float f) {
  union { float f; unsigned u; } v; v.f = f;
  unsigned r = (v.u + 0x7FFFu + ((v.u >> 16) & 1u)) >> 16;
  return (unsigned short)r;
}
__device__ __forceinline__ float bf2f(unsigned short s) {
  union { unsigned u; float f; } v; v.u = (unsigned)s << 16; return v.f;
}
__device__ __forceinline__ float bflo(unsigned u) {
  union { unsigned u; float f; } v; v.u = u << 16; return v.f;
}
__device__ __forceinline__ float bfhi(unsigned u) {
  union { unsigned u; float f; } v; v.u = u & 0xFFFF0000u; return v.f;
}

// fast softplus via HW exp/log
__device__ __forceinline__ float softplus_f(float x) {
  return fmaxf(x, 0.f) + __logf(1.f + __expf(-fabsf(x)));
}

// ---- one-time: Wt[n][k] = bf16(W[k][n]); Wdbct[j][k] = bf16(Wdbc[k][j]) ----
__global__ __launch_bounds__(256) void convert_w_k(
    const float* __restrict__ W, const float* __restrict__ Wdbc,
    unsigned short* __restrict__ Wt, unsigned short* __restrict__ Wdbct)
{
  const int k = blockIdx.x;
  const int n = threadIdx.x;
  Wt[n * 256 + k] = f2bf(W[k * 256 + n]);
  if (n < 48) Wdbct[n * 256 + k] = f2bf(Wdbc[k * 48 + n]);
}

// ------------- MEGA-FUSED (half-chunk): gemm1 (32-row tile incl. halo) -> lin LDS;
//   conv3+silu; dbc via MFMA; delta; pack->dxc; scan pass1 (16 steps) from LDS.
//   Block = one half-chunk (b,ch). 1024 blocks x 512 thr, 33.8 KB LDS -> 4 blk/CU. -------------
__global__ __launch_bounds__(512) void conv_all_k(
    const float* __restrict__ x, const float* __restrict__ conv_w,
    const float* __restrict__ conv_b, const unsigned short* __restrict__ Wt,
    const unsigned short* __restrict__ Wdbct,
    const float* __restrict__ Wdt, const float* __restrict__ bdt,
    const float* __restrict__ A_log, const float* __restrict__ bias,
    unsigned short* __restrict__ lin16, unsigned* __restrict__ dxc,
    float* __restrict__ Bm, float* __restrict__ Cm,
    float* __restrict__ Pp, float* __restrict__ Sp)
{
  __shared__ __align__(16) char smA[16896];  // xsa[32][264] -> xcb[16][264]+dlow+Bsh
  __shared__ __align__(16) char smB[16896];  // linb[32][264] -> dlt[16][264]
  unsigned short (*xsa)[264]  = (unsigned short(*)[264])smA;
  unsigned short (*xcb)[264]  = (unsigned short(*)[264])smA;
  float (*dlow)[17] = (float(*)[17])(smA + 8448);
  float (*Bsh)[17]  = (float(*)[17])(smA + 8448 + 1088);
  unsigned short (*linb)[264] = (unsigned short(*)[264])smB;
  unsigned short (*dlt)[264]  = (unsigned short(*)[264])smB;

  const int blk = blockIdx.x;               // b*NCH + ch
  const int b  = blk >> 8;
  const int ch = blk & (NCH - 1);
  const int l0 = ch * LCH;
  const int tid = threadIdx.x;
  const int lane = tid & 63, w = tid >> 6;
  const int l15 = lane & 15, lg = lane >> 4;
  const int kk = lg * 8;

  // ---- phase 0a: stage x rows (l0-8 .. l0+23, clamped) as bf16 ----
  for (int q = tid; q < 32 * 64; q += 512) {
    const int row = q >> 6, f4 = (q & 63) * 4;
    int g = b * L_ + l0 - 8 + row;
    g = g < 0 ? 0 : (g >= M_ ? M_ - 1 : g);
    const float4 v = *(const float4*)(x + (size_t)g * 256 + f4);
    ushort4 bv;
    bv.x = f2bf(v.x); bv.y = f2bf(v.y); bv.z = f2bf(v.z); bv.w = f2bf(v.w);
    *(ushort4*)&xsa[row][f4] = bv;
  }
  __syncthreads();

  // ---- phase 0b: lin tile = xsa @ W + bias (wave w: cols w*32..+31, 2 row-groups) ----
  {
    const int c0w = w * 32;
    floatx4 acc[2][2];
    #pragma unroll
    for (int rg = 0; rg < 2; ++rg)
      #pragma unroll
      for (int f = 0; f < 2; ++f) acc[rg][f] = (floatx4){0.f, 0.f, 0.f, 0.f};
    #pragma unroll
    for (int ks = 0; ks < 8; ++ks) {
      const short8 af0 = *(const short8*)&xsa[ 0 + l15][ks * 32 + kk];
      const short8 af1 = *(const short8*)&xsa[16 + l15][ks * 32 + kk];
      #pragma unroll
      for (int f = 0; f < 2; ++f) {
        const short8 bf_ = *(const short8*)(Wt + (c0w + f * 16 + l15) * 256 + ks * 32 + kk);
        acc[0][f] = __builtin_amdgcn_mfma_f32_16x16x32_bf16(af0, bf_, acc[0][f], 0, 0, 0);
        acc[1][f] = __builtin_amdgcn_mfma_f32_16x16x32_bf16(af1, bf_, acc[1][f], 0, 0, 0);
      }
    }
    __syncthreads();   // drain xsa reads (region A reusable after this)
    #pragma unroll
    for (int rg = 0; rg < 2; ++rg)
      #pragma unroll
      for (int f = 0; f < 2; ++f) {
        const int col = c0w + f * 16 + l15;
        const float bb = bias[col];
        #pragma unroll
        for (int r = 0; r < 4; ++r)
          linb[rg * 16 + lg * 4 + r][col] = f2bf(acc[rg][f][r] + bb);
      }
  }
  __syncthreads();

  // ---- phase 1: conv + bias + silu from linb; bf16 lin row -> global; xcb -> region A ----
  for (int q = tid; q < 16 * 64; q += 512) {
    const int r = q >> 6, dq = (q & 63) * 4;
    const int l = l0 + r;
    const int lr = r + 8;
    const ushort4 z = {0, 0, 0, 0};
    const ushort4 c0u = (l > 0)      ? *(const ushort4*)&linb[lr - 1][dq] : z;
    const ushort4 c1u = *(const ushort4*)&linb[lr][dq];
    const ushort4 c2u = (l < L_ - 1) ? *(const ushort4*)&linb[lr + 1][dq] : z;
    *(ushort4*)(lin16 + (size_t)(b * L_ + l) * D_ + dq) = c1u;    // gate input for GEMM2
    float4 v;
    v.x = silu_f(bf2f(c0u.x)*conv_w[(dq+0)*3+0] + bf2f(c1u.x)*conv_w[(dq+0)*3+1] + bf2f(c2u.x)*conv_w[(dq+0)*3+2] + conv_b[dq+0]);
    v.y = silu_f(bf2f(c0u.y)*conv_w[(dq+1)*3+0] + bf2f(c1u.y)*conv_w[(dq+1)*3+1] + bf2f(c2u.y)*conv_w[(dq+1)*3+2] + conv_b[dq+1]);
    v.z = silu_f(bf2f(c0u.z)*conv_w[(dq+2)*3+0] + bf2f(c1u.z)*conv_w[(dq+2)*3+1] + bf2f(c2u.z)*conv_w[(dq+2)*3+2] + conv_b[dq+2]);
    v.w = silu_f(bf2f(c0u.w)*conv_w[(dq+3)*3+0] + bf2f(c1u.w)*conv_w[(dq+3)*3+1] + bf2f(c2u.w)*conv_w[(dq+3)*3+2] + conv_b[dq+3]);
    ushort4 bv;
    bv.x = f2bf(v.x); bv.y = f2bf(v.y); bv.z = f2bf(v.z); bv.w = f2bf(v.w);
    *(ushort4*)&xcb[r][dq] = bv;
  }
  __syncthreads();   // drain linb reads (region B reusable after this)

  // ---- phase 2: dbc GEMM via MFMA (wave 0, rows 0-15) ----
  if (w == 0) {
    floatx4 acc[3];
    #pragma unroll
    for (int nt = 0; nt < 3; ++nt) acc[nt] = (floatx4){0.f, 0.f, 0.f, 0.f};
    #pragma unroll
    for (int ks = 0; ks < 8; ++ks) {
      const short8 af = *(const short8*)&xcb[l15][ks * 32 + kk];
      #pragma unroll
      for (int nt = 0; nt < 3; ++nt) {
        const short8 bf_ = *(const short8*)(Wdbct + (nt * 16 + l15) * 256 + ks * 32 + kk);
        acc[nt] = __builtin_amdgcn_mfma_f32_16x16x32_bf16(af, bf_, acc[nt], 0, 0, 0);
      }
    }
    const int row = lg * 4;
    const int gl = (b * L_ + l0 + row) * N_ + l15;
    #pragma unroll
    for (int r = 0; r < 4; ++r) {
      dlow[row + r][l15]   = acc[0][r];
      Bsh[row + r][l15]    = acc[1][r];
      Bm[gl + r * N_]      = acc[1][r];
      Cm[gl + r * N_]      = acc[2][r];
    }
  }
  __syncthreads();

  // ---- phase 3: delta = softplus(dlow @ W_dt + b_dt); bf16 -> dlt; pack -> dxc ----
  for (int q = tid; q < 16 * 64; q += 512) {
    const int r = q >> 6, dq = (q & 63) * 4;
    float4 s = *(const float4*)(bdt + dq);
    #pragma unroll
    for (int k = 0; k < DTR; ++k) {
      const float f = dlow[r][k];
      const float4 wv = *(const float4*)(Wdt + k * D_ + dq);
      s.x = fmaf(f, wv.x, s.x); s.y = fmaf(f, wv.y, s.y);
      s.z = fmaf(f, wv.z, s.z); s.w = fmaf(f, wv.w, s.w);
    }
    ushort4 dv;
    dv.x = f2bf(softplus_f(s.x)); dv.y = f2bf(softplus_f(s.y));
    dv.z = f2bf(softplus_f(s.z)); dv.w = f2bf(softplus_f(s.w));
    *(ushort4*)&dlt[r][dq] = dv;
    uint4 o;
    o.x = (unsigned)dv.x | ((unsigned)xcb[r][dq + 0] << 16);
    o.y = (unsigned)dv.y | ((unsigned)xcb[r][dq + 1] << 16);
    o.z = (unsigned)dv.z | ((unsigned)xcb[r][dq + 2] << 16);
    o.w = (unsigned)dv.w | ((unsigned)xcb[r][dq + 3] << 16);
    *(uint4*)(dxc + (size_t)(b * L_ + (l0 + r)) * D_ + dq) = o;
  }
  __syncthreads();

  // ---- phase 4: scan pass1 for this half-chunk (16 steps) from LDS ----
  {
    const int nh = tid & 1, d = tid >> 1, n0 = nh * 8;
    float A[8], P[8], S[8];
    bool fast = true;
    #pragma unroll
    for (int n = 0; n < 8; ++n) {
      A[n] = -__expf(A_log[d * N_ + n0 + n]);
      const float k = (float)(n0 + n + 1);
      fast = fast && (fabsf(A[n] + k) < 1e-3f * k);
      P[n] = 1.f; S[n] = 0.f;
    }
    if (fast) {
      float sumdv = 0.f;
      for (int t = 0; t < LCH; ++t) {
        const float dv = bf2f(dlt[t][d]);
        const float xv = bf2f(xcb[t][d]);
        const float dvx = dv * xv;
        const float rr = __expf(-dv);
        sumdv += dv;
        float a;
        if (nh) { const float r2 = rr * rr, r4 = r2 * r2; a = r4 * r4 * rr; } // r^9
        else    a = rr;                                                       // r^1
        #pragma unroll
        for (int n = 0; n < 8; ++n) {
          S[n] = fmaf(a, S[n], dvx * Bsh[t][n0 + n]);
          a *= rr;
        }
      }
      const float R = __expf(-sumdv);
      float pr;
      if (nh) { const float R2 = R * R, R4 = R2 * R2; pr = R4 * R4 * R; }
      else    pr = R;
      #pragma unroll
      for (int n = 0; n < 8; ++n) { P[n] = pr; pr *= R; }
    } else {
      for (int t = 0; t < LCH; ++t) {
        const float dv = bf2f(dlt[t][d]);
        const float xv = bf2f(xcb[t][d]);
        const float dvx = dv * xv;
        #pragma unroll
        for (int n = 0; n < 8; ++n) {
          const float a = __expf(dv * A[n]);
          S[n] = fmaf(a, S[n], dvx * Bsh[t][n0 + n]);
          P[n] *= a;
        }
      }
    }
    const int o = ((b * D_ + d) * NCH + ch) * N_ + n0;
    *(float4*)(Pp + o)     = *(const float4*)&P[0];
    *(float4*)(Pp + o + 4) = *(const float4*)&P[4];
    *(float4*)(Sp + o)     = *(const float4*)&S[0];
    *(float4*)(Sp + o + 4) = *(const float4*)&S[4];
  }
}

// pass2: block per (b,d); Hillis-Steele over 256 half-chunks (affine compose)
__global__ __launch_bounds__(256) void scan_pass2_k(
    const float* Pp, const float* Sp, float* Hin)
{
  __shared__ float lP[N_][NCH + 1];     // 16.4 KB
  __shared__ float lS[N_][NCH + 1];     // 16.4 KB
  const int bd = blockIdx.x;            // b*D + d
  const int c = threadIdx.x;            // half-chunk
  const int base = bd * NCH * N_ + c * N_;
  float P[N_], S[N_];
  #pragma unroll
  for (int q = 0; q < 4; ++q) {
    *(float4*)&P[q * 4] = *(const float4*)(Pp + base + q * 4);
    *(float4*)&S[q * 4] = *(const float4*)(Sp + base + q * 4);
  }
  #pragma unroll
  for (int n = 0; n < N_; ++n) { lP[n][c] = P[n]; lS[n][c] = S[n]; }
  for (int s = 1; s < NCH; s <<= 1) {
    __syncthreads();
    float Pb[N_], Sb[N_];
    if (c >= s) {
      #pragma unroll
      for (int n = 0; n < N_; ++n) { Pb[n] = lP[n][c - s]; Sb[n] = lS[n][c - s]; }
    }
    __syncthreads();
    if (c >= s) {
      #pragma unroll
      for (int n = 0; n < N_; ++n) {
        S[n] = fmaf(P[n], Sb[n], S[n]);   // (P,S) ∘ (Pb,Sb)
        P[n] *= Pb[n];
        lP[n][c] = P[n]; lS[n][c] = S[n];
      }
    }
  }
  __syncthreads();
  float h[N_];
  if (c == 0) {
    #pragma unroll
    for (int n = 0; n < N_; ++n) h[n] = 0.f;
  } else {
    #pragma unroll
    for (int n = 0; n < N_; ++n) h[n] = lS[n][c - 1];
  }
  #pragma unroll
  for (int q = 0; q < 4; ++q)
    *(float4*)(Hin + base + q * 4) = *(const float4*)&h[q * 4];
}

// ------------- FUSED pass3 + GEMM2: scan chunk -> y (LDS) -> gate -> MFMA -> out ---
// block = (b, c): 32 l-rows x 256 d = one GEMM A-tile. 512 threads (8 waves).
// B/C chunk tiles staged in LDS; gate reads bf16 lin16. Hin at half-chunk 2c.
__global__ __launch_bounds__(512) void scan3_gemm2_k(
    const unsigned* __restrict__ dxc,
    const float* __restrict__ Bm, const float* __restrict__ Cm,
    const float* __restrict__ A_log, const float* __restrict__ Dskip,
    const float* __restrict__ Hin, const unsigned short* __restrict__ lin16,
    const float* __restrict__ xin, const unsigned short* __restrict__ Wt,
    const float* __restrict__ bias, float* __restrict__ out)
{
  __shared__ unsigned short Asl[32][264];   // 16.9 KB: y, then gated A (bf16)
  __shared__ unsigned short Wsl[256][40];   // 20.6 KB
  __shared__ float Bs[LC][N_];              //  2 KB
  __shared__ float Cs[LC][N_];              //  2 KB
  const int blk = blockIdx.x;               // b*NC + c
  const int b = blk >> 7, c = blk & (NC - 1);
  const int tid = threadIdx.x;
  const int row0 = blk * 32;                // M-row base

  // stage B/C chunk tiles (coalesced, one sweep: 512 threads = 32*16 elems)
  {
    const int src = (b * L_ + c * LC) * N_ + tid;
    Bs[tid >> 4][tid & 15] = Bm[src];
    Cs[tid >> 4][tid & 15] = Cm[src];
  }
  __syncthreads();

  // ---- phase A: scan chunk (split-2, fast-exp), y -> Asl bf16 ----
  {
    const int nh = tid & 1, d = tid >> 1, n0 = nh * 8;
    const float dsk = Dskip[d];
    float A[8], h[8];
    bool fast = true;
    const int ho = ((b * D_ + d) * NCH + 2 * c) * N_ + n0;
    #pragma unroll
    for (int n = 0; n < 8; ++n) {
      A[n] = -__expf(A_log[d * N_ + n0 + n]);
      const float k = (float)(n0 + n + 1);
      fast = fast && (fabsf(A[n] + k) < 1e-3f * k);
    }
    *(float4*)&h[0] = *(const float4*)(Hin + ho);
    *(float4*)&h[4] = *(const float4*)(Hin + ho + 4);
    int base = (b * L_ + c * LC) * D_ + d;
    unsigned u = dxc[base];
    if (fast) {
      #pragma unroll 4
      for (int t = 0; t < LC; ++t) {
        const unsigned u_n = (t < LC - 1) ? dxc[base + D_] : 0u;   // prefetch
        const float dv = bflo(u), xv = bfhi(u);
        const float dvx = dv * xv;
        float bv[8], cv[8];
        *(float4*)&bv[0] = *(const float4*)&Bs[t][n0];
        *(float4*)&bv[4] = *(const float4*)&Bs[t][n0 + 4];
        *(float4*)&cv[0] = *(const float4*)&Cs[t][n0];
        *(float4*)&cv[4] = *(const float4*)&Cs[t][n0 + 4];
        const float r = __expf(-dv);
        float a;
        if (nh) { const float r2 = r * r, r4 = r2 * r2; a = r4 * r4 * r; }  // r^9
        else    a = r;                                                      // r^1
        float p = 0.f;
        #pragma unroll
        for (int n = 0; n < 8; ++n) {
          h[n] = fmaf(a, h[n], dvx * bv[n]);
          p = fmaf(h[n], cv[n], p);
          a *= r;
        }
        p += __shfl_xor(p, 1);
        if (nh == 0) Asl[t][d] = f2bf(fmaf(dsk, xv, p));
        u = u_n; base += D_;
      }
    } else {
      for (int t = 0; t < LC; ++t) {
        const unsigned uu = dxc[base];
        const float dvv = bflo(uu);
        const float xvv = bfhi(uu);
        const float dvx = dvv * xvv;
        float bv[8], cv[8];
        *(float4*)&bv[0] = *(const float4*)&Bs[t][n0];
        *(float4*)&bv[4] = *(const float4*)&Bs[t][n0 + 4];
        *(float4*)&cv[0] = *(const float4*)&Cs[t][n0];
        *(float4*)&cv[4] = *(const float4*)&Cs[t][n0 + 4];
        float p = 0.f;
        #pragma unroll
        for (int n = 0; n < 8; ++n) {
          const float a = __expf(dvv * A[n]);
          h[n] = fmaf(a, h[n], dvx * bv[n]);
          p = fmaf(h[n], cv[n], p);
        }
        p += __shfl_xor(p, 1);
        if (nh == 0) Asl[t][d] = f2bf(fmaf(dsk, xvv, p));
        base += D_;
      }
    }
  }
  __syncthreads();

  // ---- phase B: gate in-place: Asl = bf16(y * silu(lin) + x) ----
  for (int q = tid; q < 32 * 64; q += 512) {
    const int r = q >> 6, dq = (q & 63) * 4;
    const int off = (row0 + r) * 256 + dq;
    const ushort4 lv = *(const ushort4*)(lin16 + off);
    const float4  xv = *(const float4*)(xin + off);
    ushort4 yv = *(const ushort4*)&Asl[r][dq];
    ushort4 av;
    av.x = f2bf(fmaf(bf2f(yv.x), silu_f(bf2f(lv.x)), xv.x));
    av.y = f2bf(fmaf(bf2f(yv.y), silu_f(bf2f(lv.y)), xv.y));
    av.z = f2bf(fmaf(bf2f(yv.z), silu_f(bf2f(lv.z)), xv.z));
    av.w = f2bf(fmaf(bf2f(yv.w), silu_f(bf2f(lv.w)), xv.w));
    *(ushort4*)&Asl[r][dq] = av;
  }

  // ---- phase C: GEMM: out[32x256] = Asl @ W + bias ----
  const int lane = tid & 63, w = tid >> 6;
  const int l15 = lane & 15, lg = lane >> 4;
  const int arow = (w & 1) * 16 + l15;
  const int ctile = (w >> 1) * 64;          // 8 waves: 2 row-groups x 4 col-quarters
  const int kk = lg * 8;
  const int wn = tid >> 1, wkc = (tid & 1) * 16;
  floatx4 acc[4];
  #pragma unroll
  for (int f = 0; f < 4; ++f) acc[f] = (floatx4){0.f, 0.f, 0.f, 0.f};

  for (int ks = 0; ks < 8; ++ks) {
    __syncthreads();
    *(uint4*)&Wsl[wn][wkc + 0] = *(const uint4*)(Wt + wn * 256 + ks * 32 + wkc);
    *(uint4*)&Wsl[wn][wkc + 8] = *(const uint4*)(Wt + wn * 256 + ks * 32 + wkc + 8);
    __syncthreads();
    const short8 af = *(const short8*)&Asl[arow][ks * 32 + kk];
    #pragma unroll
    for (int f = 0; f < 4; ++f) {
      const short8 bf_ = *(const short8*)&Wsl[ctile + f * 16 + l15][kk];
      acc[f] = __builtin_amdgcn_mfma_f32_16x16x32_bf16(af, bf_, acc[f], 0, 0, 0);
    }
  }
  const int growb = row0 + (w & 1) * 16 + lg * 4;
  #pragma unroll
  for (int f = 0; f < 4; ++f) {
    const int col = ctile + f * 16 + l15;
    const float bb = bias[col];
    #pragma unroll
    for (int r = 0; r < 4; ++r)
      out[(growb + r) * 256 + col] = acc[f][r] + bb;
  }
}

extern "C" void kernel_launch(void* const* d_in, const int* in_sizes, int n_in,
                              void* d_out, int out_size, void* d_ws, size_t ws_size,
                              hipStream_t stream) {
  const float* x      = (const float*)d_in[0];
  const float* W_proj = (const float*)d_in[1];
  const float* b_proj = (const float*)d_in[2];
  const float* conv_w = (const float*)d_in[3];
  const float* conv_b = (const float*)d_in[4];
  const float* W_dbc  = (const float*)d_in[5];
  const float* W_dt   = (const float*)d_in[6];
  const float* b_dt   = (const float*)d_in[7];
  const float* A_log  = (const float*)d_in[8];
  const float* D_skip = (const float*)d_in[9];
  float* out = (float*)d_out;

  float* ws    = (float*)d_ws;
  const size_t SZ = (size_t)M_ * D_;        // 4M elements
  unsigned short* lin16 = (unsigned short*)ws;   // 8 MB bf16 (16MB slot)
  unsigned* dxc = (unsigned*)(ws + SZ);      // 16 MB packed bf16 pair
  float*    Pp  = ws + 2 * SZ;               // 16 MB (B*D*NCH*N = 4M floats)
  float*    Sp  = ws + 3 * SZ;               // 16 MB
  float*    Hin = Pp;                        // pass2 reads Pp[i] before writing Hin[i]
  float*    Bm  = ws + 4 * SZ;               // 4 MB
  float*    Cm  = Bm + (size_t)M_ * N_;      // 4 MB
  unsigned short* Wt    = (unsigned short*)(Cm + (size_t)M_ * N_);  // 128 KB
  unsigned short* Wdbct = Wt + 256 * 256;                           // 24.6 KB

  convert_w_k<<<dim3(256), dim3(256), 0, stream>>>(W_proj, W_dbc, Wt, Wdbct);
  conv_all_k<<<dim3(B_ * NCH), dim3(512), 0, stream>>>(
      x, conv_w, conv_b, Wt, Wdbct, W_dt, b_dt, A_log, b_proj,
      lin16, dxc, Bm, Cm, Pp, Sp);
  scan_pass2_k<<<dim3(B_ * D_), dim3(256), 0, stream>>>(Pp, Sp, Hin);
  scan3_gemm2_k<<<dim3(512), dim3(512), 0, stream>>>(
      dxc, Bm, Cm, A_log, D_skip, Hin, lin16, x, Wt, b_proj, out);
}

// Round 28
// 78.362 us; speedup vs baseline: 1.2406x; 1.2406x over previous
//
#include <hip/hip_runtime.h>
#include <math.h>

#define B_ 4
#define L_ 4096
#define D_ 256
#define N_ 16
#define DTR 16
#define NC 128
#define LC 32
#define M_ (B_*L_)

typedef __attribute__((ext_vector_type(8))) short short8;
typedef __attribute__((ext_vector_type(4))) float floatx4;

__device__ __forceinline__ float silu_f(float v) { return v / (1.f + __expf(-v)); }

__device__ __forceinline__ unsigned short f2bf(float f) {
  union { float f; unsigned u; } v; v.f = f;
  unsigned r = (v.u + 0x7FFFu + ((v.u >> 16) & 1u)) >> 16;
  return (unsigned short)r;
}
__device__ __forceinline__ float bf2f(unsigned short s) {
  union { unsigned u; float f; } v; v.u = (unsigned)s << 16; return v.f;
}
__device__ __forceinline__ float bflo(unsigned u) {
  union { unsigned u; float f; } v; v.u = u << 16; return v.f;
}
__device__ __forceinline__ float bfhi(unsigned u) {
  union { unsigned u; float f; } v; v.u = u & 0xFFFF0000u; return v.f;
}

// fast softplus via HW exp/log
__device__ __forceinline__ float softplus_f(float x) {
  return fmaxf(x, 0.f) + __logf(1.f + __expf(-fabsf(x)));
}

// ---- one-time: Wt[n][k] = bf16(W[k][n]); Wdbct[j][k] = bf16(Wdbc[k][j]) ----
__global__ __launch_bounds__(256) void convert_w_k(
    const float* __restrict__ W, const float* __restrict__ Wdbc,
    unsigned short* __restrict__ Wt, unsigned short* __restrict__ Wdbct)
{
  const int k = blockIdx.x;
  const int n = threadIdx.x;
  Wt[n * 256 + k] = f2bf(W[k * 256 + n]);
  if (n < 48) Wdbct[n * 256 + k] = f2bf(Wdbc[k * 48 + n]);
}

// ------------- MEGA-FUSED: gemm1 (x@W+b, 48-row tile incl. halo) -> lin LDS;
//   conv3+silu -> xcb; dbc via MFMA (Wdbct global); delta; pack->dxc;
//   scan pass1 from LDS. Block = one scan chunk (b,c). 512 thr, 66 KB LDS. -------------
__global__ __launch_bounds__(512) void conv_all_k(
    const float* __restrict__ x, const float* __restrict__ conv_w,
    const float* __restrict__ conv_b, const unsigned short* __restrict__ Wt,
    const unsigned short* __restrict__ Wdbct,
    const float* __restrict__ Wdt, const float* __restrict__ bdt,
    const float* __restrict__ A_log, const float* __restrict__ bias,
    unsigned short* __restrict__ lin16, unsigned* __restrict__ dxc,
    float* __restrict__ Bm, float* __restrict__ Cm,
    float* __restrict__ Pp, float* __restrict__ Sp)
{
  // region A (25344 B): xsa[48][264] in phase 0; {dlt[32][264], dlow[32][17], Bsh[32][17]} after
  __shared__ __align__(16) char smA[25344];
  __shared__ unsigned short linb[48][264];   // 25344 B (bf16 lin tile, rows l0-8..l0+39)
  __shared__ unsigned short xcb[32][264];    // 16896 B (bf16 conv output)
  unsigned short (*xsa)[264] = (unsigned short(*)[264])smA;
  unsigned short (*dlt)[264] = (unsigned short(*)[264])smA;
  float (*dlow)[17] = (float(*)[17])(smA + 16896);
  float (*Bsh)[17]  = (float(*)[17])(smA + 16896 + 2176);

  const int blk = blockIdx.x;               // b*NC + c
  const int b  = blk >> 7;
  const int c  = blk & (NC - 1);
  const int l0 = c * LC;
  const int tid = threadIdx.x;
  const int lane = tid & 63, w = tid >> 6;
  const int l15 = lane & 15, lg = lane >> 4;
  const int kk = lg * 8;

  // ---- phase 0a: stage x rows (l0-8 .. l0+39, clamped) as bf16 ----
  for (int q = tid; q < 48 * 64; q += 512) {
    const int row = q >> 6, f4 = (q & 63) * 4;
    int g = b * L_ + l0 - 8 + row;
    g = g < 0 ? 0 : (g >= M_ ? M_ - 1 : g);
    const float4 v = *(const float4*)(x + (size_t)g * 256 + f4);
    ushort4 bv;
    bv.x = f2bf(v.x); bv.y = f2bf(v.y); bv.z = f2bf(v.z); bv.w = f2bf(v.w);
    *(ushort4*)&xsa[row][f4] = bv;
  }
  __syncthreads();

  // ---- phase 0b: lin tile = xsa @ W + bias (wave w: cols w*32..+31, 3 row-groups) ----
  {
    const int c0w = w * 32;
    floatx4 acc[3][2];
    #pragma unroll
    for (int rg = 0; rg < 3; ++rg)
      #pragma unroll
      for (int f = 0; f < 2; ++f) acc[rg][f] = (floatx4){0.f, 0.f, 0.f, 0.f};
    #pragma unroll
    for (int ks = 0; ks < 8; ++ks) {
      const short8 af0 = *(const short8*)&xsa[ 0 + l15][ks * 32 + kk];
      const short8 af1 = *(const short8*)&xsa[16 + l15][ks * 32 + kk];
      const short8 af2 = *(const short8*)&xsa[32 + l15][ks * 32 + kk];
      #pragma unroll
      for (int f = 0; f < 2; ++f) {
        const short8 bf_ = *(const short8*)(Wt + (c0w + f * 16 + l15) * 256 + ks * 32 + kk);
        acc[0][f] = __builtin_amdgcn_mfma_f32_16x16x32_bf16(af0, bf_, acc[0][f], 0, 0, 0);
        acc[1][f] = __builtin_amdgcn_mfma_f32_16x16x32_bf16(af1, bf_, acc[1][f], 0, 0, 0);
        acc[2][f] = __builtin_amdgcn_mfma_f32_16x16x32_bf16(af2, bf_, acc[2][f], 0, 0, 0);
      }
    }
    __syncthreads();   // drain all xsa reads (region A becomes reusable after this)
    #pragma unroll
    for (int rg = 0; rg < 3; ++rg)
      #pragma unroll
      for (int f = 0; f < 2; ++f) {
        const int col = c0w + f * 16 + l15;
        const float bb = bias[col];
        #pragma unroll
        for (int r = 0; r < 4; ++r)
          linb[rg * 16 + lg * 4 + r][col] = f2bf(acc[rg][f][r] + bb);
      }
  }
  __syncthreads();

  // ---- phase 1: conv + bias + silu from linb; bf16 lin row -> global; xcb -> LDS ----
  for (int q = tid; q < 32 * 64; q += 512) {
    const int r = q >> 6, dq = (q & 63) * 4;
    const int l = l0 + r;
    const int lr = r + 8;
    const ushort4 z = {0, 0, 0, 0};
    const ushort4 c0u = (l > 0)      ? *(const ushort4*)&linb[lr - 1][dq] : z;
    const ushort4 c1u = *(const ushort4*)&linb[lr][dq];
    const ushort4 c2u = (l < L_ - 1) ? *(const ushort4*)&linb[lr + 1][dq] : z;
    *(ushort4*)(lin16 + (size_t)(b * L_ + l) * D_ + dq) = c1u;    // gate input for GEMM2
    float4 v;
    v.x = silu_f(bf2f(c0u.x)*conv_w[(dq+0)*3+0] + bf2f(c1u.x)*conv_w[(dq+0)*3+1] + bf2f(c2u.x)*conv_w[(dq+0)*3+2] + conv_b[dq+0]);
    v.y = silu_f(bf2f(c0u.y)*conv_w[(dq+1)*3+0] + bf2f(c1u.y)*conv_w[(dq+1)*3+1] + bf2f(c2u.y)*conv_w[(dq+1)*3+2] + conv_b[dq+1]);
    v.z = silu_f(bf2f(c0u.z)*conv_w[(dq+2)*3+0] + bf2f(c1u.z)*conv_w[(dq+2)*3+1] + bf2f(c2u.z)*conv_w[(dq+2)*3+2] + conv_b[dq+2]);
    v.w = silu_f(bf2f(c0u.w)*conv_w[(dq+3)*3+0] + bf2f(c1u.w)*conv_w[(dq+3)*3+1] + bf2f(c2u.w)*conv_w[(dq+3)*3+2] + conv_b[dq+3]);
    ushort4 bv;
    bv.x = f2bf(v.x); bv.y = f2bf(v.y); bv.z = f2bf(v.z); bv.w = f2bf(v.w);
    *(ushort4*)&xcb[r][dq] = bv;
  }
  __syncthreads();

  // ---- phase 2: dbc GEMM via MFMA (waves 0-1); writes dlow/Bsh (xsa region, now dead) ----
  if (w < 2) {
    const int arow = w * 16 + l15;
    floatx4 acc[3];
    #pragma unroll
    for (int nt = 0; nt < 3; ++nt) acc[nt] = (floatx4){0.f, 0.f, 0.f, 0.f};
    #pragma unroll
    for (int ks = 0; ks < 8; ++ks) {
      const short8 af = *(const short8*)&xcb[arow][ks * 32 + kk];
      #pragma unroll
      for (int nt = 0; nt < 3; ++nt) {
        const short8 bf_ = *(const short8*)(Wdbct + (nt * 16 + l15) * 256 + ks * 32 + kk);
        acc[nt] = __builtin_amdgcn_mfma_f32_16x16x32_bf16(af, bf_, acc[nt], 0, 0, 0);
      }
    }
    const int row = w * 16 + lg * 4;
    const int gl = (b * L_ + l0 + row) * N_ + l15;
    #pragma unroll
    for (int r = 0; r < 4; ++r) {
      dlow[row + r][l15]   = acc[0][r];
      Bsh[row + r][l15]    = acc[1][r];
      Bm[gl + r * N_]      = acc[1][r];
      Cm[gl + r * N_]      = acc[2][r];
    }
  }
  __syncthreads();

  // ---- phase 3: delta = softplus(dlow @ W_dt + b_dt); bf16 -> dlt; pack -> dxc ----
  for (int q = tid; q < 32 * 64; q += 512) {
    const int r = q >> 6, dq = (q & 63) * 4;
    float4 s = *(const float4*)(bdt + dq);
    #pragma unroll
    for (int k = 0; k < DTR; ++k) {
      const float f = dlow[r][k];
      const float4 wv = *(const float4*)(Wdt + k * D_ + dq);
      s.x = fmaf(f, wv.x, s.x); s.y = fmaf(f, wv.y, s.y);
      s.z = fmaf(f, wv.z, s.z); s.w = fmaf(f, wv.w, s.w);
    }
    ushort4 dv;
    dv.x = f2bf(softplus_f(s.x)); dv.y = f2bf(softplus_f(s.y));
    dv.z = f2bf(softplus_f(s.z)); dv.w = f2bf(softplus_f(s.w));
    *(ushort4*)&dlt[r][dq] = dv;
    uint4 o;
    o.x = (unsigned)dv.x | ((unsigned)xcb[r][dq + 0] << 16);
    o.y = (unsigned)dv.y | ((unsigned)xcb[r][dq + 1] << 16);
    o.z = (unsigned)dv.z | ((unsigned)xcb[r][dq + 2] << 16);
    o.w = (unsigned)dv.w | ((unsigned)xcb[r][dq + 3] << 16);
    *(uint4*)(dxc + (size_t)(b * L_ + (l0 + r)) * D_ + dq) = o;
  }
  __syncthreads();

  // ---- phase 4: scan pass1 for this chunk from LDS; N split across 2 threads ----
  {
    const int nh = tid & 1, d = tid >> 1, n0 = nh * 8;
    float A[8], P[8], S[8];
    bool fast = true;
    #pragma unroll
    for (int n = 0; n < 8; ++n) {
      A[n] = -__expf(A_log[d * N_ + n0 + n]);
      const float k = (float)(n0 + n + 1);
      fast = fast && (fabsf(A[n] + k) < 1e-3f * k);
      P[n] = 1.f; S[n] = 0.f;
    }
    if (fast) {
      float sumdv = 0.f;
      for (int t = 0; t < LC; ++t) {
        const float dv = bf2f(dlt[t][d]);
        const float xv = bf2f(xcb[t][d]);
        const float dvx = dv * xv;
        const float rr = __expf(-dv);
        sumdv += dv;
        float a;
        if (nh) { const float r2 = rr * rr, r4 = r2 * r2; a = r4 * r4 * rr; } // r^9
        else    a = rr;                                                       // r^1
        #pragma unroll
        for (int n = 0; n < 8; ++n) {
          S[n] = fmaf(a, S[n], dvx * Bsh[t][n0 + n]);
          a *= rr;
        }
      }
      const float R = __expf(-sumdv);
      float pr;
      if (nh) { const float R2 = R * R, R4 = R2 * R2; pr = R4 * R4 * R; }
      else    pr = R;
      #pragma unroll
      for (int n = 0; n < 8; ++n) { P[n] = pr; pr *= R; }
    } else {
      for (int t = 0; t < LC; ++t) {
        const float dv = bf2f(dlt[t][d]);
        const float xv = bf2f(xcb[t][d]);
        const float dvx = dv * xv;
        #pragma unroll
        for (int n = 0; n < 8; ++n) {
          const float a = __expf(dv * A[n]);
          S[n] = fmaf(a, S[n], dvx * Bsh[t][n0 + n]);
          P[n] *= a;
        }
      }
    }
    const int o = ((b * D_ + d) * NC + c) * N_ + n0;
    *(float4*)(Pp + o)     = *(const float4*)&P[0];
    *(float4*)(Pp + o + 4) = *(const float4*)&P[4];
    *(float4*)(Sp + o)     = *(const float4*)&S[0];
    *(float4*)(Sp + o + 4) = *(const float4*)&S[4];
  }
}

// pass2: block per (b,d); Hillis-Steele scan over 128 chunks (affine compose)
__global__ __launch_bounds__(128) void scan_pass2_k(
    const float* Pp, const float* Sp, float* Hin)
{
  __shared__ float lP[N_][NC + 1];
  __shared__ float lS[N_][NC + 1];
  const int bd = blockIdx.x;                 // b*D + d
  const int c = threadIdx.x;                 // chunk
  const int base = bd * NC * N_ + c * N_;
  float P[N_], S[N_];
  #pragma unroll
  for (int q = 0; q < 4; ++q) {
    *(float4*)&P[q * 4] = *(const float4*)(Pp + base + q * 4);
    *(float4*)&S[q * 4] = *(const float4*)(Sp + base + q * 4);
  }
  #pragma unroll
  for (int n = 0; n < N_; ++n) { lP[n][c] = P[n]; lS[n][c] = S[n]; }
  for (int s = 1; s < NC; s <<= 1) {
    __syncthreads();
    float Pb[N_], Sb[N_];
    if (c >= s) {
      #pragma unroll
      for (int n = 0; n < N_; ++n) { Pb[n] = lP[n][c - s]; Sb[n] = lS[n][c - s]; }
    }
    __syncthreads();
    if (c >= s) {
      #pragma unroll
      for (int n = 0; n < N_; ++n) {
        S[n] = fmaf(P[n], Sb[n], S[n]);   // (P,S) ∘ (Pb,Sb)
        P[n] *= Pb[n];
        lP[n][c] = P[n]; lS[n][c] = S[n];
      }
    }
  }
  __syncthreads();
  float h[N_];
  if (c == 0) {
    #pragma unroll
    for (int n = 0; n < N_; ++n) h[n] = 0.f;
  } else {
    #pragma unroll
    for (int n = 0; n < N_; ++n) h[n] = lS[n][c - 1];
  }
  #pragma unroll
  for (int q = 0; q < 4; ++q)
    *(float4*)(Hin + base + q * 4) = *(const float4*)&h[q * 4];
}

// ------------- FUSED pass3 + GEMM2: scan chunk -> y (LDS) -> gate -> MFMA -> out ---
// block = (b, c): 32 l-rows x 256 d = one GEMM A-tile. 512 threads (8 waves).
// B/C chunk tiles staged in LDS; gate reads bf16 lin16.
__global__ __launch_bounds__(512) void scan3_gemm2_k(
    const unsigned* __restrict__ dxc,
    const float* __restrict__ Bm, const float* __restrict__ Cm,
    const float* __restrict__ A_log, const float* __restrict__ Dskip,
    const float* __restrict__ Hin, const unsigned short* __restrict__ lin16,
    const float* __restrict__ xin, const unsigned short* __restrict__ Wt,
    const float* __restrict__ bias, float* __restrict__ out)
{
  __shared__ unsigned short Asl[32][264];   // 16.9 KB: y, then gated A (bf16)
  __shared__ unsigned short Wsl[256][40];   // 20.6 KB
  __shared__ float Bs[LC][N_];              //  2 KB
  __shared__ float Cs[LC][N_];              //  2 KB
  const int blk = blockIdx.x;               // b*NC + c
  const int b = blk >> 7, c = blk & (NC - 1);
  const int tid = threadIdx.x;
  const int row0 = blk * 32;                // M-row base

  // stage B/C chunk tiles (coalesced, one sweep: 512 threads = 32*16 elems)
  {
    const int src = (b * L_ + c * LC) * N_ + tid;
    Bs[tid >> 4][tid & 15] = Bm[src];
    Cs[tid >> 4][tid & 15] = Cm[src];
  }
  __syncthreads();

  // ---- phase A: scan chunk (split-2, fast-exp), y -> Asl bf16 ----
  {
    const int nh = tid & 1, d = tid >> 1, n0 = nh * 8;
    const float dsk = Dskip[d];
    float A[8], h[8];
    bool fast = true;
    const int ho = ((b * D_ + d) * NC + c) * N_ + n0;
    #pragma unroll
    for (int n = 0; n < 8; ++n) {
      A[n] = -__expf(A_log[d * N_ + n0 + n]);
      const float k = (float)(n0 + n + 1);
      fast = fast && (fabsf(A[n] + k) < 1e-3f * k);
    }
    *(float4*)&h[0] = *(const float4*)(Hin + ho);
    *(float4*)&h[4] = *(const float4*)(Hin + ho + 4);
    int base = (b * L_ + c * LC) * D_ + d;
    unsigned u = dxc[base];
    if (fast) {
      #pragma unroll 4
      for (int t = 0; t < LC; ++t) {
        const unsigned u_n = (t < LC - 1) ? dxc[base + D_] : 0u;   // prefetch
        const float dv = bflo(u), xv = bfhi(u);
        const float dvx = dv * xv;
        float bv[8], cv[8];
        *(float4*)&bv[0] = *(const float4*)&Bs[t][n0];
        *(float4*)&bv[4] = *(const float4*)&Bs[t][n0 + 4];
        *(float4*)&cv[0] = *(const float4*)&Cs[t][n0];
        *(float4*)&cv[4] = *(const float4*)&Cs[t][n0 + 4];
        const float r = __expf(-dv);
        float a;
        if (nh) { const float r2 = r * r, r4 = r2 * r2; a = r4 * r4 * r; }  // r^9
        else    a = r;                                                      // r^1
        float p = 0.f;
        #pragma unroll
        for (int n = 0; n < 8; ++n) {
          h[n] = fmaf(a, h[n], dvx * bv[n]);
          p = fmaf(h[n], cv[n], p);
          a *= r;
        }
        p += __shfl_xor(p, 1);
        if (nh == 0) Asl[t][d] = f2bf(fmaf(dsk, xv, p));
        u = u_n; base += D_;
      }
    } else {
      for (int t = 0; t < LC; ++t) {
        const unsigned uu = dxc[base];
        const float dvv = bflo(uu);
        const float xvv = bfhi(uu);
        const float dvx = dvv * xvv;
        float bv[8], cv[8];
        *(float4*)&bv[0] = *(const float4*)&Bs[t][n0];
        *(float4*)&bv[4] = *(const float4*)&Bs[t][n0 + 4];
        *(float4*)&cv[0] = *(const float4*)&Cs[t][n0];
        *(float4*)&cv[4] = *(const float4*)&Cs[t][n0 + 4];
        float p = 0.f;
        #pragma unroll
        for (int n = 0; n < 8; ++n) {
          const float a = __expf(dvv * A[n]);
          h[n] = fmaf(a, h[n], dvx * bv[n]);
          p = fmaf(h[n], cv[n], p);
        }
        p += __shfl_xor(p, 1);
        if (nh == 0) Asl[t][d] = f2bf(fmaf(dsk, xvv, p));
        base += D_;
      }
    }
  }
  __syncthreads();

  // ---- phase B: gate in-place: Asl = bf16(y * silu(lin) + x) ----
  for (int q = tid; q < 32 * 64; q += 512) {
    const int r = q >> 6, dq = (q & 63) * 4;
    const int off = (row0 + r) * 256 + dq;
    const ushort4 lv = *(const ushort4*)(lin16 + off);
    const float4  xv = *(const float4*)(xin + off);
    ushort4 yv = *(const ushort4*)&Asl[r][dq];
    ushort4 av;
    av.x = f2bf(fmaf(bf2f(yv.x), silu_f(bf2f(lv.x)), xv.x));
    av.y = f2bf(fmaf(bf2f(yv.y), silu_f(bf2f(lv.y)), xv.y));
    av.z = f2bf(fmaf(bf2f(yv.z), silu_f(bf2f(lv.z)), xv.z));
    av.w = f2bf(fmaf(bf2f(yv.w), silu_f(bf2f(lv.w)), xv.w));
    *(ushort4*)&Asl[r][dq] = av;
  }

  // ---- phase C: GEMM: out[32x256] = Asl @ W + bias ----
  const int lane = tid & 63, w = tid >> 6;
  const int l15 = lane & 15, lg = lane >> 4;
  const int arow = (w & 1) * 16 + l15;
  const int ctile = (w >> 1) * 64;          // 8 waves: 2 row-groups x 4 col-quarters
  const int kk = lg * 8;
  const int wn = tid >> 1, wkc = (tid & 1) * 16;
  floatx4 acc[4];
  #pragma unroll
  for (int f = 0; f < 4; ++f) acc[f] = (floatx4){0.f, 0.f, 0.f, 0.f};

  for (int ks = 0; ks < 8; ++ks) {
    __syncthreads();
    *(uint4*)&Wsl[wn][wkc + 0] = *(const uint4*)(Wt + wn * 256 + ks * 32 + wkc);
    *(uint4*)&Wsl[wn][wkc + 8] = *(const uint4*)(Wt + wn * 256 + ks * 32 + wkc + 8);
    __syncthreads();
    const short8 af = *(const short8*)&Asl[arow][ks * 32 + kk];
    #pragma unroll
    for (int f = 0; f < 4; ++f) {
      const short8 bf_ = *(const short8*)&Wsl[ctile + f * 16 + l15][kk];
      acc[f] = __builtin_amdgcn_mfma_f32_16x16x32_bf16(af, bf_, acc[f], 0, 0, 0);
    }
  }
  const int growb = row0 + (w & 1) * 16 + lg * 4;
  #pragma unroll
  for (int f = 0; f < 4; ++f) {
    const int col = ctile + f * 16 + l15;
    const float bb = bias[col];
    #pragma unroll
    for (int r = 0; r < 4; ++r)
      out[(growb + r) * 256 + col] = acc[f][r] + bb;
  }
}

extern "C" void kernel_launch(void* const* d_in, const int* in_sizes, int n_in,
                              void* d_out, int out_size, void* d_ws, size_t ws_size,
                              hipStream_t stream) {
  const float* x      = (const float*)d_in[0];
  const float* W_proj = (const float*)d_in[1];
  const float* b_proj = (const float*)d_in[2];
  const float* conv_w = (const float*)d_in[3];
  const float* conv_b = (const float*)d_in[4];
  const float* W_dbc  = (const float*)d_in[5];
  const float* W_dt   = (const float*)d_in[6];
  const float* b_dt   = (const float*)d_in[7];
  const float* A_log  = (const float*)d_in[8];
  const float* D_skip = (const float*)d_in[9];
  float* out = (float*)d_out;

  float* ws    = (float*)d_ws;
  const size_t SZ = (size_t)M_ * D_;        // 4M elements
  const size_t PSZ = (size_t)B_ * D_ * NC * N_;   // 2M floats
  unsigned short* lin16 = (unsigned short*)ws;   // 8 MB bf16 (16MB slot)
  unsigned* dxc = (unsigned*)(ws + SZ);      // 16 MB packed bf16 pair
  float*    Pp  = ws + 2 * SZ;               // Pp + Sp = 4M floats (16 MB)
  float*    Sp  = Pp + PSZ;
  float*    Hin = Pp;                        // pass2 reads Pp[i] before writing Hin[i]
  float*    Bm  = ws + 3 * SZ;               // 4 MB
  float*    Cm  = Bm + (size_t)M_ * N_;      // 4 MB
  unsigned short* Wt    = (unsigned short*)(Cm + (size_t)M_ * N_);  // 128 KB
  unsigned short* Wdbct = Wt + 256 * 256;                           // 24.6 KB

  convert_w_k<<<dim3(256), dim3(256), 0, stream>>>(W_proj, W_dbc, Wt, Wdbct);
  conv_all_k<<<dim3(512), dim3(512), 0, stream>>>(
      x, conv_w, conv_b, Wt, Wdbct, W_dt, b_dt, A_log, b_proj,
      lin16, dxc, Bm, Cm, Pp, Sp);
  scan_pass2_k<<<dim3(1024), dim3(128), 0, stream>>>(Pp, Sp, Hin);
  scan3_gemm2_k<<<dim3(512), dim3(512), 0, stream>>>(
      dxc, Bm, Cm, A_log, D_skip, Hin, lin16, x, Wt, b_proj, out);
}